// Round 1
// baseline (377.441 us; speedup 1.0000x reference)
//
#include <hip/hip_runtime.h>

// MHA: B=4, S=2048, D=1024, H=16, Dh=64.  M = B*S = 8192.
// bf16 MFMA layouts (verified):
//   16x16x32  C/D: col=lane&15, row=(lane>>4)*4+reg ; A[m=lane&15][k=(lane>>4)*8+j]
//   32x32x16  C/D: col=lane&31, row=(r&3)+8*(r>>2)+4*(lane>>5)
//             A[m=lane&31][k=(lane>>5)*8+j] ; B[k=(lane>>5)*8+j][n=lane&31]
// Flash v6: 32x32x16 MFMA + fully in-register P via v_permlane32_swap_b32 (T12).
// No Ps LDS buffer (LDS 50KB->32KB), no l-MFMAs (VALU row-sum + epilogue shfl),
// LDS-staged K/V (global_load_lds 16B + XOR-chunk swizzle), ping-pong double
// buffer -> ONE barrier/iter with warm vmcnt drain.

typedef short bf16x8 __attribute__((ext_vector_type(8)));
typedef short bf16x4 __attribute__((ext_vector_type(4)));
typedef float f32x4 __attribute__((ext_vector_type(4)));
typedef float f32x16 __attribute__((ext_vector_type(16)));
typedef unsigned int u32x4 __attribute__((ext_vector_type(4)));

__device__ __forceinline__ short f2bf(float x) {  // RNE
    union { float f; unsigned int u; } un; un.f = x;
    unsigned int u = un.u;
    return (short)(unsigned short)((u + 0x7fffu + ((u >> 16) & 1u)) >> 16);
}

__device__ __forceinline__ void gll16(const void* g, void* l) {
    __builtin_amdgcn_global_load_lds(
        (const __attribute__((address_space(1))) void*)g,
        (__attribute__((address_space(3))) void*)l, 16, 0, 0);
}

// v_permlane32_swap_b32 a, b :  tmp = a.hi32lanes; a.hi = b.lo; b.lo = tmp
__device__ __forceinline__ void plswap(unsigned& a, unsigned& b) {
    asm("v_permlane32_swap_b32 %0, %1" : "+v"(a), "+v"(b));
}

// ---- fused fp32 -> bf16 convert ----
struct CvtArgs { const float* s[4]; unsigned short* d[4]; int n4; };
__global__ __launch_bounds__(256) void cvt_bf16(CvtArgs ca) {
    const float* s = ca.s[blockIdx.y];
    unsigned short* d = ca.d[blockIdx.y];
    int i = blockIdx.x * blockDim.x + threadIdx.x;
    int stride = gridDim.x * blockDim.x;
    const float4* s4 = reinterpret_cast<const float4*>(s);
    bf16x4* d4 = reinterpret_cast<bf16x4*>(d);
    for (; i < ca.n4; i += stride) {
        float4 x = s4[i];
        bf16x4 y;
        y[0] = f2bf(x.x); y[1] = f2bf(x.y); y[2] = f2bf(x.z); y[3] = f2bf(x.w);
        d4[i] = y;
    }
}

// ---- GEMM core: C[8192][1024] = A @ W^T, val = (acc+bias)*scale ----
// mode 0: fp32 [M][N] ; mode 1: bf16 [b*16+h][s][d] ; mode 2: bf16 [b*16+h][d][s]
__device__ __forceinline__ void gemm_core(const unsigned short* __restrict__ A,
                                          const unsigned short* __restrict__ W,
                                          const float* __restrict__ bias,
                                          float scale, void* __restrict__ out,
                                          int mode) {
    __shared__ unsigned short As[128 * 64];  // 128 rows x 128B, source-swizzled
    __shared__ unsigned short Bs[128 * 64];
    const int tid = threadIdx.x;
    const int m0 = blockIdx.y * 128, n0 = blockIdx.x * 128;
    const int wave = tid >> 6, lane = tid & 63;
    const int wm = (wave >> 1) * 64, wn = (wave & 1) * 64;
    const int l15 = lane & 15, quad = lane >> 4;
    const int srow = tid >> 3;
    const int scol = ((tid & 7) ^ (srow & 7)) * 8;
    const int cb = (l15 & 7);

    f32x4 acc[4][4] = {};

    for (int k0 = 0; k0 < 1024; k0 += 64) {
        __syncthreads();
#pragma unroll
        for (int ro = 0; ro < 4; ++ro) {
            gll16(&A[(size_t)(m0 + ro * 32 + srow) * 1024 + k0 + scol], &As[ro * 2048 + tid * 8]);
            gll16(&W[(size_t)(n0 + ro * 32 + srow) * 1024 + k0 + scol], &Bs[ro * 2048 + tid * 8]);
        }
        __syncthreads();
#pragma unroll
        for (int kk = 0; kk < 2; ++kk) {
            const int co = ((4 * kk + quad) ^ cb) * 8;
            bf16x8 a[4], b[4];
#pragma unroll
            for (int i = 0; i < 4; ++i)
                a[i] = *reinterpret_cast<bf16x8*>(&As[(wm + i * 16 + l15) * 64 + co]);
#pragma unroll
            for (int j = 0; j < 4; ++j)
                b[j] = *reinterpret_cast<bf16x8*>(&Bs[(wn + j * 16 + l15) * 64 + co]);
#pragma unroll
            for (int i = 0; i < 4; ++i)
#pragma unroll
                for (int j = 0; j < 4; ++j)
                    acc[i][j] = __builtin_amdgcn_mfma_f32_16x16x32_bf16(a[i], b[j], acc[i][j], 0, 0, 0);
        }
    }

#pragma unroll
    for (int i = 0; i < 4; ++i) {
#pragma unroll
        for (int j = 0; j < 4; ++j) {
#pragma unroll
            for (int r = 0; r < 4; ++r) {
                int m = m0 + wm + i * 16 + quad * 4 + r;
                int n = n0 + wn + j * 16 + l15;
                float val = (acc[i][j][r] + bias[n]) * scale;
                if (mode == 0) {
                    reinterpret_cast<float*>(out)[(size_t)m * 1024 + n] = val;
                } else {
                    int b_ = m >> 11, s = m & 2047, h = n >> 6, d = n & 63;
                    size_t off = (mode == 1)
                                     ? ((size_t)((b_ * 16 + h) * 2048 + s) * 64 + d)
                                     : ((size_t)((b_ * 16 + h) * 64 + d) * 2048 + s);
                    reinterpret_cast<unsigned short*>(out)[off] = (unsigned short)f2bf(val);
                }
            }
        }
    }
}

struct QkvArgs {
    const unsigned short* A[3];
    const unsigned short* W[3];
    const float* bias[3];
    float scale[3];
    unsigned short* out[3];
    int mode[3];
};
__global__ __launch_bounds__(256) void gemm_qkv(QkvArgs ga) {
    int z = blockIdx.z;
    gemm_core(ga.A[z], ga.W[z], ga.bias[z], ga.scale[z], ga.out[z], ga.mode[z]);
}

__global__ __launch_bounds__(256) void gemm_wo(const unsigned short* __restrict__ A,
                                               const unsigned short* __restrict__ W,
                                               const float* __restrict__ bias,
                                               float* __restrict__ out) {
    gemm_core(A, W, bias, 1.0f, out, 0);
}

// ---- Flash v6: 32x32x16, in-register P ----
// Qh,Kh: [64][2048][64]; Vt: [64][64][2048]; Oa: [8192][1024] bf16.
// Q pre-scaled by 0.125*log2(e) -> exp2 directly. Block = (bh, 128 q), 4 waves,
// each wave owns 32 q columns. Per kv-tile (64):
//   S^T[kv][q] = K·Q^T : A=K (LDS), B=Q (regs), 2 mt x 4 kchunks = 8 MFMA
//   p = exp2(s) in regs -> pack bf16 pairs -> 4 permlane32_swap per mt
//   O[q][d] += P·V : A=P (regs!), B=V^T (LDS), 4 kvchunks x 2 dtiles = 8 MFMA
//   l += row-sum(p) on VALU (lane's kv subset; cross-half shfl at epilogue)
__global__ __launch_bounds__(256, 3) void flash_attn(const unsigned short* __restrict__ Qh,
                                                     const unsigned short* __restrict__ Kh,
                                                     const unsigned short* __restrict__ Vt,
                                                     unsigned short* __restrict__ Oa) {
    __shared__ unsigned short Ks[2][64 * 64];   // [kv][d], source-swizzled chunks
    __shared__ unsigned short Vs[2][64 * 64];   // V^T window [d][kv]
    const int tid = threadIdx.x;
    const int bh = blockIdx.y;
    const int q0 = blockIdx.x * 128;
    const unsigned short* Qb = Qh + (size_t)bh * 2048 * 64;
    const unsigned short* Kb = Kh + (size_t)bh * 2048 * 64;
    const unsigned short* Vb = Vt + (size_t)bh * 64 * 2048;
    const int wave = tid >> 6, lane = tid & 63;
    const int l31 = lane & 31, hi = lane >> 5;
    const int wq = wave * 32;
    const int srow = tid >> 3;                       // 0..31 per round
    const int scol = ((tid & 7) ^ (srow & 7)) * 8;   // swizzled source chunk

    // per-lane LDS read offsets (in shorts): row stride 64, chunk XOR row&7
    int chx[4], rowoff[2];
#pragma unroll
    for (int c = 0; c < 4; ++c) chx[c] = ((c * 2 + hi) ^ (l31 & 7)) * 8;
    rowoff[0] = l31 * 64;
    rowoff[1] = (32 + l31) * 64;

    // Q fragments (B-operand): qreg[c] = Q[q0+wq+l31][c*16 + hi*8 .. +8]
    bf16x8 qreg[4];
#pragma unroll
    for (int c = 0; c < 4; ++c)
        qreg[c] = *reinterpret_cast<const bf16x8*>(
            &Qb[(size_t)(q0 + wq + l31) * 64 + c * 16 + hi * 8]);

    f32x16 o[2] = {};
    float lacc = 0.f;

    // prologue: stage tile 0
#pragma unroll
    for (int ro = 0; ro < 2; ++ro) {
        gll16(&Kb[(size_t)(ro * 32 + srow) * 64 + scol], &Ks[0][ro * 2048 + tid * 8]);
        gll16(&Vb[(size_t)(ro * 32 + srow) * 2048 + scol], &Vs[0][ro * 2048 + tid * 8]);
    }
    __syncthreads();

    for (int it = 0; it < 32; ++it) {
        const int buf = it & 1;
        if (it < 31) {  // prefetch tile it+1 into the other buffer (no barrier)
            int kvn = (it + 1) * 64;
#pragma unroll
            for (int ro = 0; ro < 2; ++ro) {
                gll16(&Kb[(size_t)(kvn + ro * 32 + srow) * 64 + scol], &Ks[buf ^ 1][ro * 2048 + tid * 8]);
                gll16(&Vb[(size_t)(ro * 32 + srow) * 2048 + kvn + scol], &Vs[buf ^ 1][ro * 2048 + tid * 8]);
            }
        }

        // S^T[kv][q] = K·Q^T ; wave owns q cols [wq, wq+32)
        f32x16 sacc[2] = {};
#pragma unroll
        for (int c = 0; c < 4; ++c) {
            bf16x8 ak0 = *reinterpret_cast<bf16x8*>(&Ks[buf][rowoff[0] + chx[c]]);
            bf16x8 ak1 = *reinterpret_cast<bf16x8*>(&Ks[buf][rowoff[1] + chx[c]]);
            sacc[0] = __builtin_amdgcn_mfma_f32_32x32x16_bf16(ak0, qreg[c], sacc[0], 0, 0, 0);
            sacc[1] = __builtin_amdgcn_mfma_f32_32x32x16_bf16(ak1, qreg[c], sacc[1], 0, 0, 0);
        }

        // exp2 -> VALU row-sum -> pack bf16 pairs -> permlane32 redistribution.
        // Lane holds P[q=wq+l31][kv = mt*32 + (r&3)+8*(r>>2)+4*hi].
        // w[t]=pack(e[2t],e[2t+1]); swap(w0,w2),(w1,w3) builds A-frag dwords 0..3
        // of kv-chunk mt*2 ; (w4,w6),(w5,w7) -> chunk mt*2+1.
        bf16x8 pa[4];
#pragma unroll
        for (int mt = 0; mt < 2; ++mt) {
            float e[16];
#pragma unroll
            for (int r = 0; r < 16; ++r) e[r] = __builtin_amdgcn_exp2f(sacc[mt][r]);
            float s01 = (e[0] + e[1]) + (e[2] + e[3]);
            float s23 = (e[4] + e[5]) + (e[6] + e[7]);
            float s45 = (e[8] + e[9]) + (e[10] + e[11]);
            float s67 = (e[12] + e[13]) + (e[14] + e[15]);
            lacc += (s01 + s23) + (s45 + s67);
            unsigned w[8];
#pragma unroll
            for (int t = 0; t < 8; ++t) {
                union { float f; unsigned u; } a0{e[2 * t]}, a1{e[2 * t + 1]};
                w[t] = __builtin_amdgcn_perm(a1.u + 0x8000u, a0.u + 0x8000u, 0x07060302u);
            }
            plswap(w[0], w[2]); plswap(w[1], w[3]);
            plswap(w[4], w[6]); plswap(w[5], w[7]);
            u32x4 t0; t0[0] = w[0]; t0[1] = w[1]; t0[2] = w[2]; t0[3] = w[3];
            u32x4 t1; t1[0] = w[4]; t1[1] = w[5]; t1[2] = w[6]; t1[3] = w[7];
            pa[mt * 2 + 0] = __builtin_bit_cast(bf16x8, t0);
            pa[mt * 2 + 1] = __builtin_bit_cast(bf16x8, t1);
        }

        // O[q][d] += P·V  (A=P regs, B=V^T from LDS)
#pragma unroll
        for (int cg = 0; cg < 4; ++cg) {
#pragma unroll
            for (int nt = 0; nt < 2; ++nt) {
                bf16x8 bv = *reinterpret_cast<bf16x8*>(&Vs[buf][rowoff[nt] + chx[cg]]);
                o[nt] = __builtin_amdgcn_mfma_f32_32x32x16_bf16(pa[cg], bv, o[nt], 0, 0, 0);
            }
        }
        __syncthreads();  // K/V[buf] reads done; prefetch DMA (vmcnt) landed
    }

    // epilogue: full l per q (cross-half add), redistribute 1/l to o's row layout
    float lfull = lacc + __shfl_xor(lacc, 32, 64);
    float rinv = 1.0f / lfull;  // valid for q = wq + l31 (both halves)
    const int b_ = bh >> 4, h = bh & 15;
#pragma unroll
    for (int r = 0; r < 16; ++r) {
        const int qrow = (r & 3) + 8 * (r >> 2) + 4 * hi;
        const float rl = __shfl(rinv, qrow, 64);
        const int s = q0 + wq + qrow;
#pragma unroll
        for (int nt = 0; nt < 2; ++nt) {
            const int d = nt * 32 + l31;
            Oa[(size_t)(b_ * 2048 + s) * 1024 + h * 64 + d] =
                (unsigned short)f2bf(o[nt][r] * rl);
        }
    }
}

extern "C" void kernel_launch(void* const* d_in, const int* in_sizes, int n_in,
                              void* d_out, int out_size, void* d_ws, size_t ws_size,
                              hipStream_t stream) {
    const float* q  = (const float*)d_in[0];
    const float* k  = (const float*)d_in[1];
    const float* v  = (const float*)d_in[2];
    const float* Wq = (const float*)d_in[3];
    const float* bq = (const float*)d_in[4];
    const float* Wk = (const float*)d_in[5];
    const float* bk = (const float*)d_in[6];
    const float* Wv = (const float*)d_in[7];
    const float* bv = (const float*)d_in[8];
    const float* Wo = (const float*)d_in[9];
    const float* bo = (const float*)d_in[10];

    const size_t E = (size_t)8192 * 1024;
    const size_t WE = (size_t)1024 * 1024;
    // aliasing (sequential dependency chain): r0=q_bf->Kh ; r1=k_bf->Vt ; r2=v_bf->Ao ; r3=Qh
    unsigned short* r0 = (unsigned short*)d_ws;
    unsigned short* r1 = r0 + E;
    unsigned short* r2 = r1 + E;
    unsigned short* r3 = r2 + E;
    unsigned short* wqb = r3 + E;
    unsigned short* wkb = wqb + WE;
    unsigned short* wvb = wkb + WE;
    unsigned short* wob = wvb + WE;

    CvtArgs ca;
    ca.s[0] = q; ca.d[0] = r0;
    ca.s[1] = k; ca.d[1] = r1;
    ca.s[2] = v; ca.d[2] = r2;
    ca.s[3] = q; ca.d[3] = r0;  // unused (grid.y = 3)
    ca.n4 = (int)(E / 4);
    cvt_bf16<<<dim3(1024, 3), 256, 0, stream>>>(ca);

    CvtArgs cw;
    cw.s[0] = Wq; cw.d[0] = wqb;
    cw.s[1] = Wk; cw.d[1] = wkb;
    cw.s[2] = Wv; cw.d[2] = wvb;
    cw.s[3] = Wo; cw.d[3] = wob;
    cw.n4 = (int)(WE / 4);
    cvt_bf16<<<dim3(256, 4), 256, 0, stream>>>(cw);

    const float QSCALE = 0.125f * 1.44269504088896340736f;  // fold log2(e) for exp2

    QkvArgs ga;
    ga.A[0] = r0; ga.W[0] = wqb; ga.bias[0] = bq; ga.scale[0] = QSCALE; ga.out[0] = r3; ga.mode[0] = 1;
    ga.A[1] = r1; ga.W[1] = wkb; ga.bias[1] = bk; ga.scale[1] = 1.0f;   ga.out[1] = r0; ga.mode[1] = 1;
    ga.A[2] = r2; ga.W[2] = wvb; ga.bias[2] = bv; ga.scale[2] = 1.0f;   ga.out[2] = r1; ga.mode[2] = 2;
    gemm_qkv<<<dim3(8, 64, 3), 256, 0, stream>>>(ga);

    flash_attn<<<dim3(16, 64), 256, 0, stream>>>(r3, r0, r1, r2);  // Ao = r2
    gemm_wo<<<dim3(8, 64), 256, 0, stream>>>(r2, wob, bo, (float*)d_out);
}